// Round 18
// baseline (283.321 us; speedup 1.0000x reference)
//
#include <hip/hip_runtime.h>
#include <hip/hip_bf16.h>

typedef __attribute__((ext_vector_type(4))) float f32x4;
typedef __attribute__((ext_vector_type(16))) float f32x16;
typedef __attribute__((ext_vector_type(8))) short short8;
typedef unsigned short u16;

#define MFMA(a, b, c) __builtin_amdgcn_mfma_f32_16x16x32_bf16((a), (b), (c), 0, 0, 0)
#define MFMA32(a, b, c) __builtin_amdgcn_mfma_f32_32x32x16_bf16((a), (b), (c), 0, 0, 0)

static constexpr int EMBED = 768;
static constexpr int NH = 12;
static constexpr int HD = 64;
static constexpr int BATCH = 8;
static constexpr int SEQ = 1024;

__device__ __forceinline__ u16 f2bu(float f) {
    __hip_bfloat16 h = __float2bfloat16(f);
    u16 u; __builtin_memcpy(&u, &h, 2); return u;
}
__device__ __forceinline__ float exp2a(float x) {
    float r; asm("v_exp_f32 %0, %1" : "=v"(r) : "v"(x)); return r;
}
__device__ __forceinline__ unsigned cvt_pk_bf16(float lo, float hi) {
    unsigned r; asm("v_cvt_pk_bf16_f32 %0, %1, %2" : "=v"(r) : "v"(lo), "v"(hi)); return r;
}
__device__ __forceinline__ void swap32(unsigned& a, unsigned& b) {
    asm volatile("v_permlane32_swap_b32 %0, %1" : "+v"(a), "+v"(b));
}
__device__ __forceinline__ short8 mk8(unsigned w0, unsigned w1, unsigned w2, unsigned w3) {
    union { unsigned u[4]; short8 s; } c;
    c.u[0] = w0; c.u[1] = w1; c.u[2] = w2; c.u[3] = w3;
    return c.s;
}

// ---------------- fp32 -> bf16 convert (all three tensors, one launch) ----------------
__global__ void cvt_all_k(const float* __restrict__ x, const float* __restrict__ w1,
                          const float* __restrict__ w2,
                          u16* __restrict__ xb, u16* __restrict__ wb, u16* __restrict__ pw) {
    const int n1 = BATCH * SEQ * EMBED;
    const int n2 = 3 * EMBED * EMBED;
    const int n3 = EMBED * EMBED;
    int i = (blockIdx.x * blockDim.x + threadIdx.x) * 4;
    const float* src; u16* dst;
    if (i < n1)            { src = x  + i;             dst = xb + i; }
    else if (i < n1 + n2)  { src = w1 + (i - n1);      dst = wb + (i - n1); }
    else if (i < n1+n2+n3) { src = w2 + (i - n1 - n2); dst = pw + (i - n1 - n2); }
    else return;
    float4 v = *reinterpret_cast<const float4*>(src);
    ushort4 o;
    o.x = f2bu(v.x); o.y = f2bu(v.y); o.z = f2bu(v.z); o.w = f2bu(v.w);
    *reinterpret_cast<ushort4*>(dst) = o;
}

// ---------------- bf16 B^T GEMM: C[M,N] = A[M,K]*Bw[N,K]^T + bias ----------------
// BM=128, BN=192 (EPI0) / 96 (EPI1), BK=64, 4 waves (2x2), 2 LDS buffers,
// counted vmcnt (EXACT: vmcnt(CPW) — the r17 failure was vmcnt(8) with CPW=7,
// leaving 1 gll of the current tile un-retired at the barrier: a latent race).
template <int EPI, int BN>
__global__ __launch_bounds__(256)
void gemm_bt_k(const u16* __restrict__ A, const u16* __restrict__ Bw,
               const float* __restrict__ bias,
               u16* __restrict__ q_out, u16* __restrict__ k_out,
               u16* __restrict__ vt_out, float* __restrict__ f_out)
{
    constexpr int BUFB = 16384 + BN * 128;
    constexpr int NCH  = 16 + BN / 8;
    constexpr int CPW  = NCH / 4;
    constexpr int WN   = BN / 2;
    constexpr int NI   = WN / 16;
    static_assert(CPW == 10 || CPW == 8 || CPW == 7 || CPW == 6, "add vmcnt literal");

    __shared__ __attribute__((aligned(16))) char smem[2 * BUFB];
    const int tid  = threadIdx.x;
    const int wave = tid >> 6, lane = tid & 63;
    const int hi   = lane >> 4, l15 = lane & 15;
    const int wr   = wave >> 1, wc = wave & 1;
    const int bm   = blockIdx.x, bn = blockIdx.y;

    f32x4 acc[4][NI] = {};

    const size_t arow0 = (size_t)bm * 128;
    const size_t brow0 = (size_t)bn * BN;

    const u16* sptr[CPW]; int dofs[CPW];
#pragma unroll
    for (int c = 0; c < CPW; ++c) {
        int ch = c * 4 + wave;
        if (ch < 16) {
            int p    = ch * 1024 + lane * 16;
            int row  = p >> 7;
            int pcol = (p & 127) ^ ((row & 7) << 4);
            sptr[c] = A + (arow0 + row) * EMBED + (pcol >> 1);
            dofs[c] = ch * 1024;
        } else {
            int p    = (ch - 16) * 1024 + lane * 16;
            int row  = p >> 7;
            int pcol = (p & 127) ^ ((row & 7) << 4);
            sptr[c] = Bw + (brow0 + row) * EMBED + (pcol >> 1);
            dofs[c] = 16384 + (ch - 16) * 1024;
        }
    }
    auto stage = [&](int buf, int kt) {
        char* base = smem + buf * BUFB;
#pragma unroll
        for (int c = 0; c < CPW; ++c)
            __builtin_amdgcn_global_load_lds(
                (const __attribute__((address_space(1))) void*)(sptr[c] + kt),
                (__attribute__((address_space(3))) void*)(base + dofs[c]), 16, 0, 0);
    };

    const int sw_l = (l15 & 7) << 4;
    int aoff[2], boff[2];
#pragma unroll
    for (int kk = 0; kk < 2; ++kk) {
        int col = (kk * 64 + hi * 16) ^ sw_l;
        aoff[kk] = (wr * 64 + l15) * 128 + col;
        boff[kk] = 16384 + (wc * WN + l15) * 128 + col;
    }

    auto comp = [&](int buf) {
        const char* base = smem + buf * BUFB;
#pragma unroll
        for (int kk = 0; kk < 2; ++kk) {
            short8 af[4], bf[NI];
#pragma unroll
            for (int mi = 0; mi < 4; ++mi)
                af[mi] = *reinterpret_cast<const short8*>(base + aoff[kk] + mi * 2048);
#pragma unroll
            for (int ni = 0; ni < NI; ++ni)
                bf[ni] = *reinterpret_cast<const short8*>(base + boff[kk] + ni * 2048);
#pragma unroll
            for (int mi = 0; mi < 4; ++mi)
#pragma unroll
                for (int ni = 0; ni < NI; ++ni)
                    acc[mi][ni] = MFMA(af[mi], bf[ni], acc[mi][ni]);
        }
    };

    auto waitvm_bar = [&]() {
        if constexpr (CPW == 10)      asm volatile("s_waitcnt vmcnt(10)" ::: "memory");
        else if constexpr (CPW == 8)  asm volatile("s_waitcnt vmcnt(8)"  ::: "memory");
        else if constexpr (CPW == 7)  asm volatile("s_waitcnt vmcnt(7)"  ::: "memory");
        else                          asm volatile("s_waitcnt vmcnt(6)"  ::: "memory");
        __builtin_amdgcn_s_barrier();
        __builtin_amdgcn_sched_barrier(0);
    };
    auto bar2 = [&]() {
        __builtin_amdgcn_sched_barrier(0);
        __builtin_amdgcn_s_barrier();
        __builtin_amdgcn_sched_barrier(0);
    };

    stage(0, 0);
#pragma unroll
    for (int tt = 0; tt < 5; ++tt) {
        stage(1, (2 * tt + 1) * 64);
        waitvm_bar();
        comp(0);
        bar2();
        stage(0, (2 * tt + 2) * 64);
        waitvm_bar();
        comp(1);
        bar2();
    }
    stage(1, 11 * 64);
    waitvm_bar();
    comp(0);
    bar2();
    asm volatile("s_waitcnt vmcnt(0)" ::: "memory");
    __builtin_amdgcn_s_barrier();
    __builtin_amdgcn_sched_barrier(0);
    comp(1);

#pragma unroll
    for (int mi = 0; mi < 4; ++mi) {
        int crow0 = bm * 128 + wr * 64 + mi * 16 + hi * 4;
#pragma unroll
        for (int ni = 0; ni < NI; ++ni) {
            int ccol = bn * BN + wc * WN + ni * 16 + l15;
            float bv = bias[ccol];
            if constexpr (EPI == 0) {
                int which = ccol / 768;
                int rem   = ccol - which * 768;
                int hh = rem >> 6, hd = rem & 63;
                int bb = crow0 >> 10, nn0 = crow0 & 1023;
                size_t bh = (size_t)(bb * NH + hh);
                if (which == 2) {
                    uint2 pk;
                    pk.x = cvt_pk_bf16(acc[mi][ni][0] + bv, acc[mi][ni][1] + bv);
                    pk.y = cvt_pk_bf16(acc[mi][ni][2] + bv, acc[mi][ni][3] + bv);
                    *reinterpret_cast<uint2*>(&vt_out[(bh * HD + hd) * SEQ + nn0]) = pk;
                } else if (which == 0) {
#pragma unroll
                    for (int r = 0; r < 4; ++r)
                        q_out[(bh * SEQ + nn0 + r) * HD + hd] =
                            f2bu((acc[mi][ni][r] + bv) * 0.18033688f); // SCALE*log2e folded
                } else {
#pragma unroll
                    for (int r = 0; r < 4; ++r)
                        k_out[(bh * SEQ + nn0 + r) * HD + hd] = f2bu(acc[mi][ni][r] + bv);
                }
            } else {
#pragma unroll
                for (int r = 0; r < 4; ++r)
                    f_out[(size_t)(crow0 + r) * EMBED + ccol] = acc[mi][ni][r] + bv;
            }
        }
    }
}

// ---------------- flash attention v12: 8 waves x 32 q (256 q-rows/block), shared K/V staging ----------------
// grid 384 = 96 bh x 4 q-chunks; 3 blocks/CU x 8 waves = 24 waves/CU (6/SIMD).
// vmcnt accounting (exact): steady-state outstanding = s(t)x2 + s(t+1)x2 = 4; vmcnt(2)
// retires all of s(t). Prologue: qf x4 ahead in queue gives extra slack.
__global__ __launch_bounds__(512, 6)
void attn_k(const u16* __restrict__ Q, const u16* __restrict__ K,
            const u16* __restrict__ Vt, u16* __restrict__ AO)
{
    __shared__ __attribute__((aligned(16))) u16 kv[3][8192]; // per buf: [0:4095]=K, [4096:8191]=V^T

    const int tid = threadIdx.x;
    const int w   = tid >> 6, lane = tid & 63;
    const int h   = lane >> 5, l31 = lane & 31;
    const int f   = blockIdx.x;
    const int xcd = f & 7, i = f >> 3;           // i in 0..47
    const int bh  = xcd * 12 + (i % 12);
    const int q0w = (i / 12) * 256 + w * 32;     // 4 q-chunks of 256 rows

    const u16* Qh = Q  + (size_t)bh * SEQ * HD;
    const u16* Kh = K  + (size_t)bh * SEQ * HD;
    const u16* Vh = Vt + (size_t)bh * HD * SEQ;

    short8 qf[4];
#pragma unroll
    for (int ds = 0; ds < 4; ++ds)
        qf[ds] = *reinterpret_cast<const short8*>(
            Qh + (size_t)(q0w + l31) * HD + ds * 16 + h * 8);
    __builtin_amdgcn_sched_barrier(0);

    // staging: 16 chunks of 1KB (8 K + 8 V), 2 per wave
    const u16* sptr[2]; int doff[2]; int sadv[2];
#pragma unroll
    for (int c = 0; c < 2; ++c) {
        int ch = c * 8 + w;                       // 0..15
        int mc = ch & 7;
        int p  = mc * 1024 + lane * 16;
        int row = p >> 7;
        int colb = (p & 127) ^ ((row & 7) << 4) ^ (((row >> 3) & 3) << 5);
        if (ch < 8) { sptr[c] = Kh + (size_t)row * HD + (colb >> 1); sadv[c] = 64 * HD; doff[c] = mc * 512; }
        else        { sptr[c] = Vh + (size_t)row * SEQ + (colb >> 1); sadv[c] = 64;     doff[c] = 4096 + mc * 512; }
    }
    auto stage = [&](int buf, int t) {            // 2 gll per wave
#pragma unroll
        for (int c = 0; c < 2; ++c)
            __builtin_amdgcn_global_load_lds(
                (const __attribute__((address_space(1))) void*)(sptr[c] + (size_t)t * sadv[c]),
                (__attribute__((address_space(3))) void*)(&kv[buf][doff[c]]), 16, 0, 0);
    };

    stage(0, 0);
    stage(1, 1);

    const int sw_l = ((l31 & 7) << 4) ^ (((l31 >> 3) & 3) << 5);
    int koff[4];
#pragma unroll
    for (int ds = 0; ds < 4; ++ds)
        koff[ds] = l31 * 128 + ((ds * 32 + h * 16) ^ sw_l);

    union { unsigned u[4]; short8 s; } oc;
    oc.u[0] = oc.u[1] = oc.u[2] = oc.u[3] = 0x3F803F80u;
    const short8 ones8 = oc.s;

    f32x16 accO[2] = {};
    f32x16 lsum = {};

    auto tile = [&](int BC) {
        const char* base = (const char*)kv + BC * 16384;
        f32x16 st[2] = {{0}, {0}};
        __builtin_amdgcn_s_setprio(1);
#pragma unroll
        for (int mf = 0; mf < 2; ++mf)
#pragma unroll
            for (int ds = 0; ds < 4; ++ds) {
                short8 kf = *reinterpret_cast<const short8*>(base + mf * 4096 + koff[ds]);
                st[mf] = MFMA32(kf, qf[ds], st[mf]);
            }
        __builtin_amdgcn_s_setprio(0);

        unsigned pkw[2][8];
#pragma unroll
        for (int mf = 0; mf < 2; ++mf)
#pragma unroll
            for (int p = 0; p < 8; ++p) {
                float e0 = exp2a(st[mf][2 * p]);
                float e1 = exp2a(st[mf][2 * p + 1]);
                pkw[mf][p] = cvt_pk_bf16(e0, e1);
            }

        short8 pb[4];
#pragma unroll
        for (int ks = 0; ks < 4; ++ks) {
            int mf = ks >> 1, b4 = (ks & 1) * 4;
            unsigned E0 = pkw[mf][b4 + 0], E1 = pkw[mf][b4 + 1];
            unsigned D0 = pkw[mf][b4 + 2], D1 = pkw[mf][b4 + 3];
            swap32(E0, D0);
            swap32(E1, D1);
            pb[ks] = mk8(E0, E1, D0, D1);
        }

        __builtin_amdgcn_s_setprio(1);
#pragma unroll
        for (int ks = 0; ks < 4; ++ks)
            lsum = MFMA32(ones8, pb[ks], lsum);
#pragma unroll
        for (int df = 0; df < 2; ++df)
#pragma unroll
            for (int ks = 0; ks < 4; ++ks) {
                short8 vf = *reinterpret_cast<const short8*>(base + 8192 + df * 4096 + koff[ks]);
                accO[df] = MFMA32(vf, pb[ks], accO[df]);
            }
        __builtin_amdgcn_s_setprio(0);
    };

    auto one = [&](int bc, int bs, int tn, bool ds) {
        asm volatile("s_waitcnt vmcnt(2)" ::: "memory");
        __builtin_amdgcn_s_barrier();
        __builtin_amdgcn_sched_barrier(0);
        if (ds) stage(bs, tn);
        tile(bc);
        __builtin_amdgcn_sched_barrier(0);
    };

    one(0, 2, 2, true);
    one(1, 0, 3, true);
    one(2, 1, 4, true);
    for (int g = 1; g < 5; ++g) {
        one(0, 2, 3 * g + 2, true);
        one(1, 0, 3 * g + 3, 3 * g + 3 <= 15);
        one(2, 1, 3 * g + 4, 3 * g + 4 <= 15);
    }
    asm volatile("s_waitcnt vmcnt(0)" ::: "memory");
    __builtin_amdgcn_s_barrier();
    __builtin_amdgcn_sched_barrier(0);
    tile(0);

    float linv = 1.f / lsum[0];
    const int bb = bh / NH, hh = bh - bb * NH;
    size_t rowb = ((size_t)bb * SEQ + q0w + l31) * EMBED + hh * HD;
#pragma unroll
    for (int df = 0; df < 2; ++df)
#pragma unroll
        for (int g = 0; g < 4; ++g) {
            float o0 = accO[df][4 * g + 0] * linv;
            float o1 = accO[df][4 * g + 1] * linv;
            float o2 = accO[df][4 * g + 2] * linv;
            float o3 = accO[df][4 * g + 3] * linv;
            uint2 pk;
            pk.x = cvt_pk_bf16(o0, o1);
            pk.y = cvt_pk_bf16(o2, o3);
            *reinterpret_cast<uint2*>(&AO[rowb + df * 32 + 8 * g + 4 * h]) = pk;
        }
}

// ---------------- launch ----------------
extern "C" void kernel_launch(void* const* d_in, const int* in_sizes, int n_in,
                              void* d_out, int out_size, void* d_ws, size_t ws_size,
                              hipStream_t stream)
{
    const float* x      = (const float*)d_in[0];
    const float* qkv_w  = (const float*)d_in[1];
    const float* qkv_b  = (const float*)d_in[2];
    const float* proj_w = (const float*)d_in[3];
    const float* proj_b = (const float*)d_in[4];
    float* out = (float*)d_out;

    char* ws = (char*)d_ws;
    u16* xb  = (u16*)(ws);
    u16* wb  = (u16*)(ws + 12582912);
    u16* pw  = (u16*)(ws + 16121856);
    u16* qb  = (u16*)(ws + 17301504);
    u16* kb  = (u16*)(ws + 29884416);
    u16* vt  = (u16*)(ws + 42467328);
    u16* ao  = (u16*)(ws + 55050240);

    cvt_all_k<<<8448, 256, 0, stream>>>(x, qkv_w, proj_w, xb, wb, pw);

    gemm_bt_k<0, 192><<<dim3(64, 12), 256, 0, stream>>>(xb, wb, qkv_b, qb, kb, vt, nullptr);
    attn_k<<<384, 512, 0, stream>>>(qb, kb, vt, ao);
    gemm_bt_k<1, 96><<<dim3(64, 8), 256, 0, stream>>>(ao, pw, proj_b, nullptr, nullptr, nullptr, out);
}

// Round 19
// 95.453 us; speedup vs baseline: 2.9682x; 2.9682x over previous
//
#include <hip/hip_runtime.h>
#include <hip/hip_bf16.h>

typedef __attribute__((ext_vector_type(4))) float f32x4;
typedef __attribute__((ext_vector_type(16))) float f32x16;
typedef __attribute__((ext_vector_type(8))) short short8;
typedef unsigned short u16;

#define MFMA(a, b, c) __builtin_amdgcn_mfma_f32_16x16x32_bf16((a), (b), (c), 0, 0, 0)
#define MFMA32(a, b, c) __builtin_amdgcn_mfma_f32_32x32x16_bf16((a), (b), (c), 0, 0, 0)

static constexpr int EMBED = 768;
static constexpr int NH = 12;
static constexpr int HD = 64;
static constexpr int BATCH = 8;
static constexpr int SEQ = 1024;

__device__ __forceinline__ u16 f2bu(float f) {
    __hip_bfloat16 h = __float2bfloat16(f);
    u16 u; __builtin_memcpy(&u, &h, 2); return u;
}
__device__ __forceinline__ float exp2a(float x) {
    float r; asm("v_exp_f32 %0, %1" : "=v"(r) : "v"(x)); return r;
}
__device__ __forceinline__ unsigned cvt_pk_bf16(float lo, float hi) {
    unsigned r; asm("v_cvt_pk_bf16_f32 %0, %1, %2" : "=v"(r) : "v"(lo), "v"(hi)); return r;
}
__device__ __forceinline__ void swap32(unsigned& a, unsigned& b) {
    asm volatile("v_permlane32_swap_b32 %0, %1" : "+v"(a), "+v"(b));
}
__device__ __forceinline__ short8 mk8(unsigned w0, unsigned w1, unsigned w2, unsigned w3) {
    union { unsigned u[4]; short8 s; } c;
    c.u[0] = w0; c.u[1] = w1; c.u[2] = w2; c.u[3] = w3;
    return c.s;
}

// ---------------- fp32 -> bf16 convert (all three tensors, one launch) ----------------
__global__ void cvt_all_k(const float* __restrict__ x, const float* __restrict__ w1,
                          const float* __restrict__ w2,
                          u16* __restrict__ xb, u16* __restrict__ wb, u16* __restrict__ pw) {
    const int n1 = BATCH * SEQ * EMBED;
    const int n2 = 3 * EMBED * EMBED;
    const int n3 = EMBED * EMBED;
    int i = (blockIdx.x * blockDim.x + threadIdx.x) * 4;
    const float* src; u16* dst;
    if (i < n1)            { src = x  + i;             dst = xb + i; }
    else if (i < n1 + n2)  { src = w1 + (i - n1);      dst = wb + (i - n1); }
    else if (i < n1+n2+n3) { src = w2 + (i - n1 - n2); dst = pw + (i - n1 - n2); }
    else return;
    float4 v = *reinterpret_cast<const float4*>(src);
    ushort4 o;
    o.x = f2bu(v.x); o.y = f2bu(v.y); o.z = f2bu(v.z); o.w = f2bu(v.w);
    *reinterpret_cast<ushort4*>(dst) = o;
}

// ---------------- bf16 B^T GEMM: C[M,N] = A[M,K]*Bw[N,K]^T + bias ----------------
// BM=128, BN=192 (EPI0) / 96 (EPI1), BK=64, 4 waves (2x2), 2 LDS buffers,
// counted vmcnt (EXACT vmcnt(CPW) literals — fixes the CPW=7 latent race).
template <int EPI, int BN>
__global__ __launch_bounds__(256)
void gemm_bt_k(const u16* __restrict__ A, const u16* __restrict__ Bw,
               const float* __restrict__ bias,
               u16* __restrict__ q_out, u16* __restrict__ k_out,
               u16* __restrict__ vt_out, float* __restrict__ f_out)
{
    constexpr int BUFB = 16384 + BN * 128;
    constexpr int NCH  = 16 + BN / 8;
    constexpr int CPW  = NCH / 4;
    constexpr int WN   = BN / 2;
    constexpr int NI   = WN / 16;
    static_assert(CPW == 10 || CPW == 8 || CPW == 7 || CPW == 6, "add vmcnt literal");

    __shared__ __attribute__((aligned(16))) char smem[2 * BUFB];
    const int tid  = threadIdx.x;
    const int wave = tid >> 6, lane = tid & 63;
    const int hi   = lane >> 4, l15 = lane & 15;
    const int wr   = wave >> 1, wc = wave & 1;
    const int bm   = blockIdx.x, bn = blockIdx.y;

    f32x4 acc[4][NI] = {};

    const size_t arow0 = (size_t)bm * 128;
    const size_t brow0 = (size_t)bn * BN;

    const u16* sptr[CPW]; int dofs[CPW];
#pragma unroll
    for (int c = 0; c < CPW; ++c) {
        int ch = c * 4 + wave;
        if (ch < 16) {
            int p    = ch * 1024 + lane * 16;
            int row  = p >> 7;
            int pcol = (p & 127) ^ ((row & 7) << 4);
            sptr[c] = A + (arow0 + row) * EMBED + (pcol >> 1);
            dofs[c] = ch * 1024;
        } else {
            int p    = (ch - 16) * 1024 + lane * 16;
            int row  = p >> 7;
            int pcol = (p & 127) ^ ((row & 7) << 4);
            sptr[c] = Bw + (brow0 + row) * EMBED + (pcol >> 1);
            dofs[c] = 16384 + (ch - 16) * 1024;
        }
    }
    auto stage = [&](int buf, int kt) {
        char* base = smem + buf * BUFB;
#pragma unroll
        for (int c = 0; c < CPW; ++c)
            __builtin_amdgcn_global_load_lds(
                (const __attribute__((address_space(1))) void*)(sptr[c] + kt),
                (__attribute__((address_space(3))) void*)(base + dofs[c]), 16, 0, 0);
    };

    const int sw_l = (l15 & 7) << 4;
    int aoff[2], boff[2];
#pragma unroll
    for (int kk = 0; kk < 2; ++kk) {
        int col = (kk * 64 + hi * 16) ^ sw_l;
        aoff[kk] = (wr * 64 + l15) * 128 + col;
        boff[kk] = 16384 + (wc * WN + l15) * 128 + col;
    }

    auto comp = [&](int buf) {
        const char* base = smem + buf * BUFB;
#pragma unroll
        for (int kk = 0; kk < 2; ++kk) {
            short8 af[4], bf[NI];
#pragma unroll
            for (int mi = 0; mi < 4; ++mi)
                af[mi] = *reinterpret_cast<const short8*>(base + aoff[kk] + mi * 2048);
#pragma unroll
            for (int ni = 0; ni < NI; ++ni)
                bf[ni] = *reinterpret_cast<const short8*>(base + boff[kk] + ni * 2048);
#pragma unroll
            for (int mi = 0; mi < 4; ++mi)
#pragma unroll
                for (int ni = 0; ni < NI; ++ni)
                    acc[mi][ni] = MFMA(af[mi], bf[ni], acc[mi][ni]);
        }
    };

    auto waitvm_bar = [&]() {
        if constexpr (CPW == 10)      asm volatile("s_waitcnt vmcnt(10)" ::: "memory");
        else if constexpr (CPW == 8)  asm volatile("s_waitcnt vmcnt(8)"  ::: "memory");
        else if constexpr (CPW == 7)  asm volatile("s_waitcnt vmcnt(7)"  ::: "memory");
        else                          asm volatile("s_waitcnt vmcnt(6)"  ::: "memory");
        __builtin_amdgcn_s_barrier();
        __builtin_amdgcn_sched_barrier(0);
    };
    auto bar2 = [&]() {
        __builtin_amdgcn_sched_barrier(0);
        __builtin_amdgcn_s_barrier();
        __builtin_amdgcn_sched_barrier(0);
    };

    stage(0, 0);
#pragma unroll
    for (int tt = 0; tt < 5; ++tt) {
        stage(1, (2 * tt + 1) * 64);
        waitvm_bar();
        comp(0);
        bar2();
        stage(0, (2 * tt + 2) * 64);
        waitvm_bar();
        comp(1);
        bar2();
    }
    stage(1, 11 * 64);
    waitvm_bar();
    comp(0);
    bar2();
    asm volatile("s_waitcnt vmcnt(0)" ::: "memory");
    __builtin_amdgcn_s_barrier();
    __builtin_amdgcn_sched_barrier(0);
    comp(1);

#pragma unroll
    for (int mi = 0; mi < 4; ++mi) {
        int crow0 = bm * 128 + wr * 64 + mi * 16 + hi * 4;
#pragma unroll
        for (int ni = 0; ni < NI; ++ni) {
            int ccol = bn * BN + wc * WN + ni * 16 + l15;
            float bv = bias[ccol];
            if constexpr (EPI == 0) {
                int which = ccol / 768;
                int rem   = ccol - which * 768;
                int hh = rem >> 6, hd = rem & 63;
                int bb = crow0 >> 10, nn0 = crow0 & 1023;
                size_t bh = (size_t)(bb * NH + hh);
                if (which == 2) {
                    uint2 pk;
                    pk.x = cvt_pk_bf16(acc[mi][ni][0] + bv, acc[mi][ni][1] + bv);
                    pk.y = cvt_pk_bf16(acc[mi][ni][2] + bv, acc[mi][ni][3] + bv);
                    *reinterpret_cast<uint2*>(&vt_out[(bh * HD + hd) * SEQ + nn0]) = pk;
                } else if (which == 0) {
#pragma unroll
                    for (int r = 0; r < 4; ++r)
                        q_out[(bh * SEQ + nn0 + r) * HD + hd] =
                            f2bu((acc[mi][ni][r] + bv) * 0.18033688f); // SCALE*log2e folded
                } else {
#pragma unroll
                    for (int r = 0; r < 4; ++r)
                        k_out[(bh * SEQ + nn0 + r) * HD + hd] = f2bu(acc[mi][ni][r] + bv);
                }
            } else {
#pragma unroll
                for (int r = 0; r < 4; ++r)
                    f_out[(size_t)(crow0 + r) * EMBED + ccol] = acc[mi][ni][r] + bv;
            }
        }
    }
}

// ---------------- flash attention v11 (r13/r14-proven): no-shift softmax, 2-level swizzle ----------------
// 4 waves x 32 q, 256 threads, 3 blocks/CU, VGPR 84 (no spill).
__global__ __launch_bounds__(256, 3)
void attn_k(const u16* __restrict__ Q, const u16* __restrict__ K,
            const u16* __restrict__ Vt, u16* __restrict__ AO)
{
    __shared__ __attribute__((aligned(16))) u16 kv[3][8192]; // per buf: [0:4095]=K, [4096:8191]=V^T

    const int tid = threadIdx.x;
    const int w   = tid >> 6, lane = tid & 63;
    const int h   = lane >> 5, l31 = lane & 31;
    const int f   = blockIdx.x;
    const int xcd = f & 7, i = f >> 3;
    const int bh  = xcd * 12 + (i % 12);
    const int q0w = (i / 12) * 128 + w * 32;

    const u16* Qh = Q  + (size_t)bh * SEQ * HD;
    const u16* Kh = K  + (size_t)bh * SEQ * HD;
    const u16* Vh = Vt + (size_t)bh * HD * SEQ;

    short8 qf[4];
#pragma unroll
    for (int ds = 0; ds < 4; ++ds)
        qf[ds] = *reinterpret_cast<const short8*>(
            Qh + (size_t)(q0w + l31) * HD + ds * 16 + h * 8);
    __builtin_amdgcn_sched_barrier(0);

    const u16* sptr[4]; int doff[4]; int sadv[4];
#pragma unroll
    for (int c = 0; c < 4; ++c) {
        int ch = c * 4 + w;
        int mc = ch & 7;
        int p  = mc * 1024 + lane * 16;
        int row = p >> 7;
        int colb = (p & 127) ^ ((row & 7) << 4) ^ (((row >> 3) & 3) << 5);
        if (ch < 8) { sptr[c] = Kh + (size_t)row * HD + (colb >> 1); sadv[c] = 64 * HD; doff[c] = mc * 512; }
        else        { sptr[c] = Vh + (size_t)row * SEQ + (colb >> 1); sadv[c] = 64;     doff[c] = 4096 + mc * 512; }
    }
    auto stage = [&](int buf, int t) {
#pragma unroll
        for (int c = 0; c < 4; ++c)
            __builtin_amdgcn_global_load_lds(
                (const __attribute__((address_space(1))) void*)(sptr[c] + (size_t)t * sadv[c]),
                (__attribute__((address_space(3))) void*)(&kv[buf][doff[c]]), 16, 0, 0);
    };

    stage(0, 0);
    stage(1, 1);

    const int sw_l = ((l31 & 7) << 4) ^ (((l31 >> 3) & 3) << 5);
    int koff[4];
#pragma unroll
    for (int ds = 0; ds < 4; ++ds)
        koff[ds] = l31 * 128 + ((ds * 32 + h * 16) ^ sw_l);

    union { unsigned u[4]; short8 s; } oc;
    oc.u[0] = oc.u[1] = oc.u[2] = oc.u[3] = 0x3F803F80u;
    const short8 ones8 = oc.s;

    f32x16 accO[2] = {};
    f32x16 lsum = {};

    auto tile = [&](int BC) {
        const char* base = (const char*)kv + BC * 16384;
        f32x16 st[2] = {{0}, {0}};
        __builtin_amdgcn_s_setprio(1);
#pragma unroll
        for (int mf = 0; mf < 2; ++mf)
#pragma unroll
            for (int ds = 0; ds < 4; ++ds) {
                short8 kf = *reinterpret_cast<const short8*>(base + mf * 4096 + koff[ds]);
                st[mf] = MFMA32(kf, qf[ds], st[mf]);
            }
        __builtin_amdgcn_s_setprio(0);

        unsigned pkw[2][8];
#pragma unroll
        for (int mf = 0; mf < 2; ++mf)
#pragma unroll
            for (int p = 0; p < 8; ++p) {
                float e0 = exp2a(st[mf][2 * p]);
                float e1 = exp2a(st[mf][2 * p + 1]);
                pkw[mf][p] = cvt_pk_bf16(e0, e1);
            }

        short8 pb[4];
#pragma unroll
        for (int ks = 0; ks < 4; ++ks) {
            int mf = ks >> 1, b4 = (ks & 1) * 4;
            unsigned E0 = pkw[mf][b4 + 0], E1 = pkw[mf][b4 + 1];
            unsigned D0 = pkw[mf][b4 + 2], D1 = pkw[mf][b4 + 3];
            swap32(E0, D0);
            swap32(E1, D1);
            pb[ks] = mk8(E0, E1, D0, D1);
        }

        __builtin_amdgcn_s_setprio(1);
#pragma unroll
        for (int ks = 0; ks < 4; ++ks)
            lsum = MFMA32(ones8, pb[ks], lsum);
#pragma unroll
        for (int df = 0; df < 2; ++df)
#pragma unroll
            for (int ks = 0; ks < 4; ++ks) {
                short8 vf = *reinterpret_cast<const short8*>(base + 8192 + df * 4096 + koff[ks]);
                accO[df] = MFMA32(vf, pb[ks], accO[df]);
            }
        __builtin_amdgcn_s_setprio(0);
    };

    auto one = [&](int bc, int bs, int tn, bool ds) {
        asm volatile("s_waitcnt vmcnt(4)" ::: "memory");
        __builtin_amdgcn_s_barrier();
        __builtin_amdgcn_sched_barrier(0);
        if (ds) stage(bs, tn);
        tile(bc);
        __builtin_amdgcn_sched_barrier(0);
    };

    one(0, 2, 2, true);
    one(1, 0, 3, true);
    one(2, 1, 4, true);
    for (int g = 1; g < 5; ++g) {
        one(0, 2, 3 * g + 2, true);
        one(1, 0, 3 * g + 3, 3 * g + 3 <= 15);
        one(2, 1, 3 * g + 4, 3 * g + 4 <= 15);
    }
    asm volatile("s_waitcnt vmcnt(0)" ::: "memory");
    __builtin_amdgcn_s_barrier();
    __builtin_amdgcn_sched_barrier(0);
    tile(0);

    float linv = 1.f / lsum[0];
    const int bb = bh / NH, hh = bh - bb * NH;
    size_t rowb = ((size_t)bb * SEQ + q0w + l31) * EMBED + hh * HD;
#pragma unroll
    for (int df = 0; df < 2; ++df)
#pragma unroll
        for (int g = 0; g < 4; ++g) {
            float o0 = accO[df][4 * g + 0] * linv;
            float o1 = accO[df][4 * g + 1] * linv;
            float o2 = accO[df][4 * g + 2] * linv;
            float o3 = accO[df][4 * g + 3] * linv;
            uint2 pk;
            pk.x = cvt_pk_bf16(o0, o1);
            pk.y = cvt_pk_bf16(o2, o3);
            *reinterpret_cast<uint2*>(&AO[rowb + df * 32 + 8 * g + 4 * h]) = pk;
        }
}

// ---------------- launch ----------------
extern "C" void kernel_launch(void* const* d_in, const int* in_sizes, int n_in,
                              void* d_out, int out_size, void* d_ws, size_t ws_size,
                              hipStream_t stream)
{
    const float* x      = (const float*)d_in[0];
    const float* qkv_w  = (const float*)d_in[1];
    const float* qkv_b  = (const float*)d_in[2];
    const float* proj_w = (const float*)d_in[3];
    const float* proj_b = (const float*)d_in[4];
    float* out = (float*)d_out;

    char* ws = (char*)d_ws;
    u16* xb  = (u16*)(ws);
    u16* wb  = (u16*)(ws + 12582912);
    u16* pw  = (u16*)(ws + 16121856);
    u16* qb  = (u16*)(ws + 17301504);
    u16* kb  = (u16*)(ws + 29884416);
    u16* vt  = (u16*)(ws + 42467328);
    u16* ao  = (u16*)(ws + 55050240);

    cvt_all_k<<<8448, 256, 0, stream>>>(x, qkv_w, proj_w, xb, wb, pw);

    gemm_bt_k<0, 192><<<dim3(64, 12), 256, 0, stream>>>(xb, wb, qkv_b, qb, kb, vt, nullptr);
    attn_k<<<768, 256, 0, stream>>>(qb, kb, vt, ao);
    gemm_bt_k<1, 96><<<dim3(64, 8), 256, 0, stream>>>(ao, pw, proj_b, nullptr, nullptr, nullptr, out);
}